// Round 11
// baseline (342.709 us; speedup 1.0000x reference)
//
// v3 resubmit (r9 source + hash-busting marker): r9/r10 failed at container
// level with no profile; audit found no kernel fault vector. If this fails,
// next round reverts to known-good round-7 source.
#include <hip/hip_runtime.h>
#include <math.h>

#define NN 50000
#define EE 800000
#define GG 512
#define OUTC 100
#define NEG 0.2f
#define STRIDE 64
#define NPART 8
#define PRNG (NN / NPART)           // 6250
#define PCHUNK 4096
#define NCHUNK 196                  // 196*4096 >= 800000
#define SCAT_BLOCKS (NPART * NCHUNK)   // 1568, %8==0

// cursor padded to one counter per 64B line (kills same-line L2 atomic serialization)
#define CSTRIDE 16

// weight block layout: 32 sub-blocks (16 hi + 16 lo) x WROWS rows x 8 ushorts.
#define WROWS 145
#define WCHUNKS 73
#define WLAYER (WCHUNKS * 512)

typedef unsigned int u32;
#define GLOBAL_AS __attribute__((address_space(1)))
#define LDS_AS __attribute__((address_space(3)))

typedef __attribute__((ext_vector_type(8))) short bf16x8;
typedef __attribute__((ext_vector_type(8))) short s16x8;
typedef __attribute__((ext_vector_type(8))) unsigned short us8;
typedef __attribute__((ext_vector_type(4))) float f32x4;
typedef __attribute__((ext_vector_type(4))) int i32x4;

__device__ inline ushort f2bf(float v) {
  unsigned u = __float_as_uint(v);
  unsigned r = (u + 0x7fff + ((u >> 16) & 1)) >> 16;
  return (ushort)r;
}

// ---- dst-partitioned scatter (padded cursor) + weight prep ----
__global__ __launch_bounds__(256) void k_scatter_prep(const int* __restrict__ ei,
    int* __restrict__ cursor, ushort* __restrict__ srcs,
    const float* __restrict__ W0, const float* __restrict__ W1, const float* __restrict__ W2,
    const float* __restrict__ as0, const float* __restrict__ as1, const float* __restrict__ as2,
    const float* __restrict__ ad0, const float* __restrict__ ad1, const float* __restrict__ ad2,
    ushort* __restrict__ wg) {
  if (blockIdx.x < SCAT_BLOCKS) {
    int part = blockIdx.x & (NPART - 1);     // == XCD under round-robin placement
    int chunk = blockIdx.x >> 3;
    int plo = part * PRNG, phi = plo + PRNG;
    int base = chunk * PCHUNK + (threadIdx.x << 2);
    int4 d[4];
    bool lv[4];
#pragma unroll
    for (int it = 0; it < 4; ++it) {         // issue all dst loads up-front
      int e = base + (it << 10);
      lv[it] = (e < EE);
      if (lv[it]) d[it] = *(const int4*)&ei[EE + e];
      else        d[it] = make_int4(-1, -1, -1, -1);
    }
#pragma unroll
    for (int it = 0; it < 4; ++it) {
      if (!lv[it]) continue;
      int e = base + (it << 10);
      int4 dd = d[it];
      bool m0 = (dd.x >= plo) & (dd.x < phi);
      bool m1 = (dd.y >= plo) & (dd.y < phi);
      bool m2 = (dd.z >= plo) & (dd.z < phi);
      bool m3 = (dd.w >= plo) & (dd.w < phi);
      if (m0 | m1 | m2 | m3) {
        int4 s4 = *(const int4*)&ei[e];
        if (m0) { int p = atomicAdd(&cursor[dd.x * CSTRIDE], 1); if (p < STRIDE) srcs[(dd.x << 6) + p] = (ushort)s4.x; }
        if (m1) { int p = atomicAdd(&cursor[dd.y * CSTRIDE], 1); if (p < STRIDE) srcs[(dd.y << 6) + p] = (ushort)s4.y; }
        if (m2) { int p = atomicAdd(&cursor[dd.z * CSTRIDE], 1); if (p < STRIDE) srcs[(dd.z << 6) + p] = (ushort)s4.z; }
        if (m3) { int p = atomicAdd(&cursor[dd.w * CSTRIDE], 1); if (p < STRIDE) srcs[(dd.w << 6) + p] = (ushort)s4.w; }
      }
    }
  } else {
    int pb = blockIdx.x - SCAT_BLOCKS;          // 0..203
    int layer = pb / 68, bx = pb % 68;
    const float* W  = (layer == 0) ? W0 : (layer == 1) ? W1 : W2;
    const float* av = (layer == 0) ? as0 : (layer == 1) ? as1 : as2;
    const float* dv = (layer == 0) ? ad0 : (layer == 1) ? ad1 : ad2;
    ushort* wgL = wg + (size_t)layer * WLAYER;
    int idx = bx * 256 + threadIdx.x;
    if (bx < 64) {
      int row = idx >> 7, col = idx & 127;
      int c = col >> 3, j = col & 7;
      float v = W[idx];
      ushort hb = f2bf(v);
      float hf = __uint_as_float(((unsigned)hb) << 16);
      wgL[((size_t)c * WROWS + row) * 8 + j] = hb;
      wgL[((size_t)(16 + c) * WROWS + row) * 8 + j] = f2bf(v - hf);
    } else {
      int j2 = idx - 64 * 256;                  // [0,1024)
      int j = j2 >> 7, k = j2 & 127;            // j: attn row 0..7, k: col
      int head = j & 3;
      const float* vec = (j < 4) ? &av[head * 32] : &dv[head * 32];
      float dot = 0.f;
#pragma unroll
      for (int c = 0; c < 32; c++) dot += W[(head * 32 + c) * 128 + k] * vec[c];
      ushort hb = f2bf(dot);
      float hf = __uint_as_float(((unsigned)hb) << 16);
      int c16 = k >> 3, jj = k & 7;
      wgL[((size_t)c16 * WROWS + 128 + j) * 8 + jj] = hb;
      wgL[((size_t)(16 + c16) * WROWS + 128 + j) * 8 + jj] = f2bf(dot - hf);
      wgL[((size_t)c16 * WROWS + 136 + j) * 8 + jj] = 0;
      wgL[((size_t)(16 + c16) * WROWS + 136 + j) * 8 + jj] = 0;
    }
  }
}

// ---- compact padded cursor (3.2 MB) into dense deg[] (200 KB) once ----
__global__ __launch_bounds__(512) void k_deg(const int* __restrict__ cursor,
    int* __restrict__ degv) {
  int n = blockIdx.x * 512 + threadIdx.x;
  if (n < NN) degv[n] = min(cursor[n * CSTRIDE], STRIDE);
}

// ---------------- GEMM: weights staged in LDS, feat hoisted to regs ----------------
__global__ __launch_bounds__(512) void k_gemm_mfma(const float* __restrict__ feat,
    const ushort* __restrict__ wg,
    short* __restrict__ hq, float* __restrict__ asp, float* __restrict__ adstf) {
  __shared__ alignas(16) ushort lds[WLAYER];
  int t = threadIdx.x;
  int wave = t >> 6, lane = t & 63;
  int quad = lane >> 4, r16 = lane & 15;

#pragma unroll
  for (int i = 0; i < 10; ++i) {
    int chunk = i * 8 + wave;
    if (chunk < WCHUNKS) {
      int off = chunk * 512 + lane * 8;
      __builtin_amdgcn_global_load_lds((const GLOBAL_AS u32*)&wg[off],
                                       (LDS_AS u32*)&lds[off], 16, 0, 0);
    }
  }

  int n0 = blockIdx.x * 128;
  int rowA = n0 + wave * 16 + r16;
  bool valid = rowA < NN;
  float4 f[8];
#pragma unroll
  for (int ks = 0; ks < 4; ++ks) {
    if (valid) {
      const float4* fp = (const float4*)&feat[(size_t)rowA * 128 + ks * 32 + quad * 8];
      f[ks * 2] = fp[0];
      f[ks * 2 + 1] = fp[1];
    } else {
      f[ks * 2] = make_float4(0.f, 0.f, 0.f, 0.f);
      f[ks * 2 + 1] = f[ks * 2];
    }
  }
  __syncthreads();

  f32x4 acc[9];
#pragma unroll
  for (int nt = 0; nt < 9; nt++) acc[nt] = (f32x4)0.f;

#pragma unroll
  for (int ks = 0; ks < 4; ks++) {
    bf16x8 ah, al;
    {
      float4 va = f[ks * 2], vb = f[ks * 2 + 1];
      float vv[8] = {va.x, va.y, va.z, va.w, vb.x, vb.y, vb.z, vb.w};
      us8 hh, ll;
#pragma unroll
      for (int j = 0; j < 8; j++) {
        ushort hb = f2bf(vv[j]);
        float hf = __uint_as_float(((unsigned)hb) << 16);
        hh[j] = hb;
        ll[j] = (ushort)(__float_as_uint(vv[j] - hf) >> 16);
      }
      ah = (bf16x8)hh;
      al = (bf16x8)ll;
    }
    int cc = ks * 4 + quad;
#pragma unroll
    for (int nt = 0; nt < 9; nt++) {
      int wrow = (nt < 8) ? (nt * 16 + r16) : (128 + r16);
      bf16x8 bh = *(const bf16x8*)&lds[((size_t)cc * WROWS + wrow) * 8];
      bf16x8 bl = *(const bf16x8*)&lds[((size_t)(16 + cc) * WROWS + wrow) * 8];
      acc[nt] = __builtin_amdgcn_mfma_f32_16x16x32_bf16(ah, bh, acc[nt], 0, 0, 0);
      acc[nt] = __builtin_amdgcn_mfma_f32_16x16x32_bf16(al, bh, acc[nt], 0, 0, 0);
      acc[nt] = __builtin_amdgcn_mfma_f32_16x16x32_bf16(ah, bl, acc[nt], 0, 0, 0);
    }
  }

#pragma unroll
  for (int reg = 0; reg < 4; reg++) {
    float am = 0.f;
#pragma unroll
    for (int nt = 0; nt < 8; nt++) am = fmaxf(am, fabsf(acc[nt][reg]));
#pragma unroll
    for (int off = 1; off < 16; off <<= 1) am = fmaxf(am, __shfl_xor(am, off));
    int node = n0 + wave * 16 + quad * 4 + reg;
    if (node < NN) {
      float amc = fmaxf(am, 1e-20f);
      float rq = 32767.f / amc;
      if (r16 < 4) asp[node * 8 + r16] = acc[8][reg];
      else if (r16 < 8) adstf[node * 4 + r16 - 4] = acc[8][reg];
      else if (r16 == 8) asp[node * 8 + 4] = amc * (1.f / 32767.f);
      short* dq = &hq[(size_t)node * 128 + r16];
#pragma unroll
      for (int nt = 0; nt < 8; nt++)
        dq[nt * 16] = (short)__float2int_rn(acc[nt][reg] * rq);
    }
  }
}

// ---------------- gather-aggregate: 3-deep pipeline (round-7 best config) ----------------
__global__ __launch_bounds__(256) void k_gather(const short* __restrict__ hq,
    const float* __restrict__ asp,
    const float4* __restrict__ adst,
    const int* __restrict__ degv, const ushort* __restrict__ srcs,
    const float* __restrict__ bias, float* __restrict__ outf) {
  __shared__ alignas(16) int   s_src[2][4][4][16];
  __shared__ alignas(16) float s_wt[2][4][4][4][20];

  int wave = threadIdx.x >> 6, lane = threadIdx.x & 63;
  int grp = lane >> 4;
  int gl = lane & 15;
  int node = blockIdx.x * 16 + wave * 4 + grp;
  int head = gl >> 2;
  int c0 = gl << 3;

  int deg = 0, e0 = 0;
  float4 ad = make_float4(0.f, 0.f, 0.f, 0.f);
  bool valid = node < NN;
  if (valid) {
    deg = degv[node];
    e0 = node << 6;
    ad = adst[node];
  }
  int rounds = (deg + 15) >> 4;

  float acc[8];
#pragma unroll
  for (int i = 0; i < 8; i++) acc[i] = 0.f;
  float ws0 = 0.f, ws1 = 0.f, ws2 = 0.f, ws3 = 0.f;
  float wself = 0.f;

  auto loadSrc = [&](int r, int& sn, int& lv) {
    int j = (r << 4) + gl;
    lv = (j < deg);
    sn = lv ? (int)srcs[e0 + j] : 0;
  };
  auto loadAsp = [&](int sn, int lv, float4& a, float& sc) {
    if (lv) {
      a = *(const float4*)&asp[sn * 8];
      sc = asp[sn * 8 + 4];
    } else {
      a = make_float4(0.f, 0.f, 0.f, 0.f);
      sc = 0.f;
    }
  };
  auto finishWrite = [&](int b, int sn, int lv, float4 a, float sc) {
    float q0 = 0.f, q1 = 0.f, q2 = 0.f, q3 = 0.f;
    if (lv) {
      float v, w0, w1, w2, w3;
      v = a.x + ad.x; v = v > 0.f ? v : NEG * v; w0 = __expf(v);
      v = a.y + ad.y; v = v > 0.f ? v : NEG * v; w1 = __expf(v);
      v = a.z + ad.z; v = v > 0.f ? v : NEG * v; w2 = __expf(v);
      v = a.w + ad.w; v = v > 0.f ? v : NEG * v; w3 = __expf(v);
      ws0 += w0; ws1 += w1; ws2 += w2; ws3 += w3;
      q0 = w0 * sc; q1 = w1 * sc; q2 = w2 * sc; q3 = w3 * sc;
    }
    s_src[b][wave][grp][gl] = sn << 7;
    s_wt[b][wave][grp][0][gl] = q0;
    s_wt[b][wave][grp][1][gl] = q1;
    s_wt[b][wave][grp][2][gl] = q2;
    s_wt[b][wave][grp][3][gl] = q3;
  };

  auto consume = [&](int r, int b) {
    int cnt2 = deg - (r << 4);
    cnt2 = min(cnt2, 16);
    const int* srow = &s_src[b][wave][grp][0];
    const float* wrow = &s_wt[b][wave][grp][head][0];
#pragma unroll
    for (int c = 0; c < 2; ++c) {
      int k0 = c << 3;
      if (k0 < cnt2) {
        int4 sa = *(const int4*)&srow[k0];
        int4 sb = *(const int4*)&srow[k0 + 4];
        float4 wa = *(const float4*)&wrow[k0];
        float4 wb = *(const float4*)&wrow[k0 + 4];
        s16x8 qa = *(const s16x8*)&hq[sa.x + c0];
        s16x8 qb = *(const s16x8*)&hq[sa.y + c0];
        s16x8 qc = *(const s16x8*)&hq[sa.z + c0];
        s16x8 qd = *(const s16x8*)&hq[sa.w + c0];
        s16x8 qe = *(const s16x8*)&hq[sb.x + c0];
        s16x8 qf = *(const s16x8*)&hq[sb.y + c0];
        s16x8 qg = *(const s16x8*)&hq[sb.z + c0];
        s16x8 qh = *(const s16x8*)&hq[sb.w + c0];
#pragma unroll
        for (int i = 0; i < 8; i++) acc[i] = fmaf(wa.x, (float)qa[i], acc[i]);
#pragma unroll
        for (int i = 0; i < 8; i++) acc[i] = fmaf(wa.y, (float)qb[i], acc[i]);
#pragma unroll
        for (int i = 0; i < 8; i++) acc[i] = fmaf(wa.z, (float)qc[i], acc[i]);
#pragma unroll
        for (int i = 0; i < 8; i++) acc[i] = fmaf(wa.w, (float)qd[i], acc[i]);
        if (k0 + 4 < cnt2) {
#pragma unroll
          for (int i = 0; i < 8; i++) acc[i] = fmaf(wb.x, (float)qe[i], acc[i]);
#pragma unroll
          for (int i = 0; i < 8; i++) acc[i] = fmaf(wb.y, (float)qf[i], acc[i]);
#pragma unroll
          for (int i = 0; i < 8; i++) acc[i] = fmaf(wb.z, (float)qg[i], acc[i]);
#pragma unroll
          for (int i = 0; i < 8; i++) acc[i] = fmaf(wb.w, (float)qh[i], acc[i]);
        }
      }
    }
  };

  int sn0 = 0, lv0 = 0, sn1 = 0, lv1 = 0, sn2 = 0, lv2 = 0;
  float4 a0; float sc0;

  if (rounds > 0) {
    loadSrc(0, sn0, lv0);
    if (rounds > 1) loadSrc(1, sn1, lv1);
    loadAsp(sn0, lv0, a0, sc0);
  }

  if (valid) {
    const float4 a = *(const float4*)&asp[node * 8];
    float sc = asp[node * 8 + 4];
    float v, w0, w1, w2, w3;
    v = a.x + ad.x; v = v > 0.f ? v : NEG * v; w0 = __expf(v);
    v = a.y + ad.y; v = v > 0.f ? v : NEG * v; w1 = __expf(v);
    v = a.z + ad.z; v = v > 0.f ? v : NEG * v; w2 = __expf(v);
    v = a.w + ad.w; v = v > 0.f ? v : NEG * v; w3 = __expf(v);
    float wh = (head == 0) ? w0 : (head == 1) ? w1 : (head == 2) ? w2 : w3;
    wself = wh;
    float wssc = wh * sc;
    s16x8 qs = *(const s16x8*)&hq[(node << 7) + c0];
#pragma unroll
    for (int i = 0; i < 8; i++) acc[i] = wssc * (float)qs[i];
  }

  if (rounds > 0) {
    finishWrite(0, sn0, lv0, a0, sc0);
    for (int r = 0; r < rounds; ++r) {
      int b = r & 1;
      if (r + 2 < rounds) loadSrc(r + 2, sn2, lv2);
      float4 aX = make_float4(0.f, 0.f, 0.f, 0.f); float scX = 0.f;
      if (r + 1 < rounds) loadAsp(sn1, lv1, aX, scX);
      consume(r, b);
      if (r + 1 < rounds) finishWrite(b ^ 1, sn1, lv1, aX, scX);
      sn1 = sn2; lv1 = lv2;
    }
  }

#pragma unroll
  for (int off = 1; off < 16; off <<= 1) {
    ws0 += __shfl_xor(ws0, off);
    ws1 += __shfl_xor(ws1, off);
    ws2 += __shfl_xor(ws2, off);
    ws3 += __shfl_xor(ws3, off);
  }

  if (valid) {
    float wsum = wself + ((head == 0) ? ws0 : (head == 1) ? ws1 : (head == 2) ? ws2 : ws3);
    float rcp = 1.f / (wsum + 1e-16f);
    float4 bv0 = *(const float4*)&bias[c0];
    float4 bv1 = *(const float4*)&bias[c0 + 4];
    float bb[8] = {bv0.x, bv0.y, bv0.z, bv0.w, bv1.x, bv1.y, bv1.z, bv1.w};
    float o[8];
#pragma unroll
    for (int i = 0; i < 8; i++) {
      float v = acc[i] * rcp + bb[i];
      o[i] = v > 0.f ? v : expm1f(v);
    }
    *(float4*)&outf[(size_t)node * 128 + c0] = make_float4(o[0], o[1], o[2], o[3]);
    *(float4*)&outf[(size_t)node * 128 + c0 + 4] = make_float4(o[4], o[5], o[6], o[7]);
  }
}

// ---------------- fused mean-pool + FC: batch sorted -> contiguous node range per graph ----------------
__global__ __launch_bounds__(128) void k_fc(const float* __restrict__ feat,
    const int* __restrict__ batchv, const float* __restrict__ fcW,
    const float* __restrict__ fcb, float* __restrict__ out) {
  int g = blockIdx.x;
  int t = threadIdx.x;
  // binary search [lo, hi) of graph g in sorted batch (redundant across threads;
  // same-address loads broadcast)
  int lo, hi;
  {
    int l = 0, r = NN;
    while (l < r) { int m = (l + r) >> 1; if (batchv[m] < g) l = m + 1; else r = m; }
    lo = l;
    r = NN;
    while (l < r) { int m = (l + r) >> 1; if (batchv[m] <= g) l = m + 1; else r = m; }
    hi = l;
  }
  float acc = 0.f;
  for (int n = lo; n < hi; ++n) acc += feat[(size_t)n * 128 + t];
  __shared__ float p[128];
  float inv = 1.f / fmaxf((float)(hi - lo), 1.f);
  p[t] = acc * inv;
  __syncthreads();
  if (t < OUTC) {
    float a = fcb[t];
    const float4* wr = (const float4*)&fcW[t * 128];
    const float4* pp = (const float4*)p;
#pragma unroll
    for (int i = 0; i < 32; i++) {
      float4 w = wr[i], pv = pp[i];
      a = fmaf(w.x, pv.x, fmaf(w.y, pv.y, fmaf(w.z, pv.z, fmaf(w.w, pv.w, a))));
    }
    out[g * OUTC + t] = a;
  }
}

extern "C" void kernel_launch(void* const* d_in, const int* in_sizes, int n_in,
                              void* d_out, int out_size, void* d_ws, size_t ws_size,
                              hipStream_t stream) {
  const float* x    = (const float*)d_in[0];
  const int*   ei   = (const int*)d_in[1];
  const int*   batch= (const int*)d_in[2];
  const float* W1   = (const float*)d_in[3];
  const float* as1  = (const float*)d_in[4];
  const float* ad1  = (const float*)d_in[5];
  const float* b1   = (const float*)d_in[6];
  const float* W2   = (const float*)d_in[7];
  const float* as2  = (const float*)d_in[8];
  const float* ad2  = (const float*)d_in[9];
  const float* b2   = (const float*)d_in[10];
  const float* W3   = (const float*)d_in[11];
  const float* as3  = (const float*)d_in[12];
  const float* ad3  = (const float*)d_in[13];
  const float* b3   = (const float*)d_in[14];
  const float* fcW  = (const float*)d_in[15];
  const float* fcb  = (const float*)d_in[16];
  float* out = (float*)d_out;

  char* p = (char*)d_ws;
  auto alloc = [&](size_t bytes) { char* r = p; p += (bytes + 255) & ~(size_t)255; return r; };
  short* hq     = (short*)alloc((size_t)NN * 128 * 2);
  float* asp    = (float*)alloc((size_t)NN * 8 * 4);
  float* buf0   = (float*)alloc((size_t)NN * 128 * 4);
  float* adstv  = (float*)alloc((size_t)NN * 4 * 4);
  int*   degv   = (int*)alloc((size_t)NN * 4);
  char*  zbase  = p;
  int*   cursor = (int*)alloc((size_t)NN * CSTRIDE * 4);   // 64B line per node
  size_t zlen   = (size_t)(p - zbase);
  ushort* srcs  = (ushort*)alloc((size_t)NN * STRIDE * 2);
  ushort* wg    = (ushort*)alloc((size_t)3 * WLAYER * 2);

  hipMemsetAsync(zbase, 0, zlen, stream);

  k_scatter_prep<<<SCAT_BLOCKS + 204, 256, 0, stream>>>(ei, cursor, srcs,
      W1, W2, W3, as1, as2, as3, ad1, ad2, ad3, wg);
  k_deg<<<(NN + 511) / 512, 512, 0, stream>>>(cursor, degv);

  const float* bs[3] = {b1, b2, b3};
  const float* fin = x;
  for (int l = 0; l < 3; l++) {
    k_gemm_mfma<<<(NN + 127) / 128, 512, 0, stream>>>(fin,
        wg + (size_t)l * WLAYER, hq, asp, adstv);
    k_gather<<<(NN + 15) / 16, 256, 0, stream>>>(hq, asp,
        (const float4*)adstv, degv, srcs, bs[l], buf0);
    fin = buf0;
  }
  k_fc<<<GG, 128, 0, stream>>>(buf0, batch, fcW, fcb, out);
}

// Round 12
// 319.331 us; speedup vs baseline: 1.0732x; 1.0732x over previous
//
// r12: consolidation — round-7 pool/fc restored; keep k_deg + dense degv gather.
#include <hip/hip_runtime.h>
#include <math.h>

#define NN 50000
#define EE 800000
#define GG 512
#define OUTC 100
#define NEG 0.2f
#define STRIDE 64
#define NPART 8
#define PRNG (NN / NPART)           // 6250
#define PCHUNK 4096
#define NCHUNK 196                  // 196*4096 >= 800000
#define SCAT_BLOCKS (NPART * NCHUNK)   // 1568, %8==0

// cursor padded to one counter per 64B line (kills same-line L2 atomic serialization)
#define CSTRIDE 16

// weight block layout: 32 sub-blocks (16 hi + 16 lo) x WROWS rows x 8 ushorts.
#define WROWS 145
#define WCHUNKS 73
#define WLAYER (WCHUNKS * 512)

typedef unsigned int u32;
#define GLOBAL_AS __attribute__((address_space(1)))
#define LDS_AS __attribute__((address_space(3)))

typedef __attribute__((ext_vector_type(8))) short bf16x8;
typedef __attribute__((ext_vector_type(8))) short s16x8;
typedef __attribute__((ext_vector_type(8))) unsigned short us8;
typedef __attribute__((ext_vector_type(4))) float f32x4;
typedef __attribute__((ext_vector_type(4))) int i32x4;

__device__ inline ushort f2bf(float v) {
  unsigned u = __float_as_uint(v);
  unsigned r = (u + 0x7fff + ((u >> 16) & 1)) >> 16;
  return (ushort)r;
}

// ---- dst-partitioned scatter (padded cursor) + weight prep ----
__global__ __launch_bounds__(256) void k_scatter_prep(const int* __restrict__ ei,
    int* __restrict__ cursor, ushort* __restrict__ srcs,
    const float* __restrict__ W0, const float* __restrict__ W1, const float* __restrict__ W2,
    const float* __restrict__ as0, const float* __restrict__ as1, const float* __restrict__ as2,
    const float* __restrict__ ad0, const float* __restrict__ ad1, const float* __restrict__ ad2,
    ushort* __restrict__ wg) {
  if (blockIdx.x < SCAT_BLOCKS) {
    int part = blockIdx.x & (NPART - 1);     // == XCD under round-robin placement
    int chunk = blockIdx.x >> 3;
    int plo = part * PRNG, phi = plo + PRNG;
    int base = chunk * PCHUNK + (threadIdx.x << 2);
    int4 d[4];
    bool lv[4];
#pragma unroll
    for (int it = 0; it < 4; ++it) {         // issue all dst loads up-front
      int e = base + (it << 10);
      lv[it] = (e < EE);
      if (lv[it]) d[it] = *(const int4*)&ei[EE + e];
      else        d[it] = make_int4(-1, -1, -1, -1);
    }
#pragma unroll
    for (int it = 0; it < 4; ++it) {
      if (!lv[it]) continue;
      int e = base + (it << 10);
      int4 dd = d[it];
      bool m0 = (dd.x >= plo) & (dd.x < phi);
      bool m1 = (dd.y >= plo) & (dd.y < phi);
      bool m2 = (dd.z >= plo) & (dd.z < phi);
      bool m3 = (dd.w >= plo) & (dd.w < phi);
      if (m0 | m1 | m2 | m3) {
        int4 s4 = *(const int4*)&ei[e];
        if (m0) { int p = atomicAdd(&cursor[dd.x * CSTRIDE], 1); if (p < STRIDE) srcs[(dd.x << 6) + p] = (ushort)s4.x; }
        if (m1) { int p = atomicAdd(&cursor[dd.y * CSTRIDE], 1); if (p < STRIDE) srcs[(dd.y << 6) + p] = (ushort)s4.y; }
        if (m2) { int p = atomicAdd(&cursor[dd.z * CSTRIDE], 1); if (p < STRIDE) srcs[(dd.z << 6) + p] = (ushort)s4.z; }
        if (m3) { int p = atomicAdd(&cursor[dd.w * CSTRIDE], 1); if (p < STRIDE) srcs[(dd.w << 6) + p] = (ushort)s4.w; }
      }
    }
  } else {
    int pb = blockIdx.x - SCAT_BLOCKS;          // 0..203
    int layer = pb / 68, bx = pb % 68;
    const float* W  = (layer == 0) ? W0 : (layer == 1) ? W1 : W2;
    const float* av = (layer == 0) ? as0 : (layer == 1) ? as1 : as2;
    const float* dv = (layer == 0) ? ad0 : (layer == 1) ? ad1 : ad2;
    ushort* wgL = wg + (size_t)layer * WLAYER;
    int idx = bx * 256 + threadIdx.x;
    if (bx < 64) {
      int row = idx >> 7, col = idx & 127;
      int c = col >> 3, j = col & 7;
      float v = W[idx];
      ushort hb = f2bf(v);
      float hf = __uint_as_float(((unsigned)hb) << 16);
      wgL[((size_t)c * WROWS + row) * 8 + j] = hb;
      wgL[((size_t)(16 + c) * WROWS + row) * 8 + j] = f2bf(v - hf);
    } else {
      int j2 = idx - 64 * 256;                  // [0,1024)
      int j = j2 >> 7, k = j2 & 127;            // j: attn row 0..7, k: col
      int head = j & 3;
      const float* vec = (j < 4) ? &av[head * 32] : &dv[head * 32];
      float dot = 0.f;
#pragma unroll
      for (int c = 0; c < 32; c++) dot += W[(head * 32 + c) * 128 + k] * vec[c];
      ushort hb = f2bf(dot);
      float hf = __uint_as_float(((unsigned)hb) << 16);
      int c16 = k >> 3, jj = k & 7;
      wgL[((size_t)c16 * WROWS + 128 + j) * 8 + jj] = hb;
      wgL[((size_t)(16 + c16) * WROWS + 128 + j) * 8 + jj] = f2bf(dot - hf);
      wgL[((size_t)c16 * WROWS + 136 + j) * 8 + jj] = 0;
      wgL[((size_t)(16 + c16) * WROWS + 136 + j) * 8 + jj] = 0;
    }
  }
}

// ---- compact padded cursor (3.2 MB) into dense deg[] (200 KB) once ----
__global__ __launch_bounds__(512) void k_deg(const int* __restrict__ cursor,
    int* __restrict__ degv) {
  int n = blockIdx.x * 512 + threadIdx.x;
  if (n < NN) degv[n] = min(cursor[n * CSTRIDE], STRIDE);
}

// ---------------- GEMM: weights staged in LDS, feat hoisted to regs ----------------
__global__ __launch_bounds__(512) void k_gemm_mfma(const float* __restrict__ feat,
    const ushort* __restrict__ wg,
    short* __restrict__ hq, float* __restrict__ asp, float* __restrict__ adstf) {
  __shared__ alignas(16) ushort lds[WLAYER];
  int t = threadIdx.x;
  int wave = t >> 6, lane = t & 63;
  int quad = lane >> 4, r16 = lane & 15;

#pragma unroll
  for (int i = 0; i < 10; ++i) {
    int chunk = i * 8 + wave;
    if (chunk < WCHUNKS) {
      int off = chunk * 512 + lane * 8;
      __builtin_amdgcn_global_load_lds((const GLOBAL_AS u32*)&wg[off],
                                       (LDS_AS u32*)&lds[off], 16, 0, 0);
    }
  }

  int n0 = blockIdx.x * 128;
  int rowA = n0 + wave * 16 + r16;
  bool valid = rowA < NN;
  float4 f[8];
#pragma unroll
  for (int ks = 0; ks < 4; ++ks) {
    if (valid) {
      const float4* fp = (const float4*)&feat[(size_t)rowA * 128 + ks * 32 + quad * 8];
      f[ks * 2] = fp[0];
      f[ks * 2 + 1] = fp[1];
    } else {
      f[ks * 2] = make_float4(0.f, 0.f, 0.f, 0.f);
      f[ks * 2 + 1] = f[ks * 2];
    }
  }
  __syncthreads();

  f32x4 acc[9];
#pragma unroll
  for (int nt = 0; nt < 9; nt++) acc[nt] = (f32x4)0.f;

#pragma unroll
  for (int ks = 0; ks < 4; ks++) {
    bf16x8 ah, al;
    {
      float4 va = f[ks * 2], vb = f[ks * 2 + 1];
      float vv[8] = {va.x, va.y, va.z, va.w, vb.x, vb.y, vb.z, vb.w};
      us8 hh, ll;
#pragma unroll
      for (int j = 0; j < 8; j++) {
        ushort hb = f2bf(vv[j]);
        float hf = __uint_as_float(((unsigned)hb) << 16);
        hh[j] = hb;
        ll[j] = (ushort)(__float_as_uint(vv[j] - hf) >> 16);
      }
      ah = (bf16x8)hh;
      al = (bf16x8)ll;
    }
    int cc = ks * 4 + quad;
#pragma unroll
    for (int nt = 0; nt < 9; nt++) {
      int wrow = (nt < 8) ? (nt * 16 + r16) : (128 + r16);
      bf16x8 bh = *(const bf16x8*)&lds[((size_t)cc * WROWS + wrow) * 8];
      bf16x8 bl = *(const bf16x8*)&lds[((size_t)(16 + cc) * WROWS + wrow) * 8];
      acc[nt] = __builtin_amdgcn_mfma_f32_16x16x32_bf16(ah, bh, acc[nt], 0, 0, 0);
      acc[nt] = __builtin_amdgcn_mfma_f32_16x16x32_bf16(al, bh, acc[nt], 0, 0, 0);
      acc[nt] = __builtin_amdgcn_mfma_f32_16x16x32_bf16(ah, bl, acc[nt], 0, 0, 0);
    }
  }

#pragma unroll
  for (int reg = 0; reg < 4; reg++) {
    float am = 0.f;
#pragma unroll
    for (int nt = 0; nt < 8; nt++) am = fmaxf(am, fabsf(acc[nt][reg]));
#pragma unroll
    for (int off = 1; off < 16; off <<= 1) am = fmaxf(am, __shfl_xor(am, off));
    int node = n0 + wave * 16 + quad * 4 + reg;
    if (node < NN) {
      float amc = fmaxf(am, 1e-20f);
      float rq = 32767.f / amc;
      if (r16 < 4) asp[node * 8 + r16] = acc[8][reg];
      else if (r16 < 8) adstf[node * 4 + r16 - 4] = acc[8][reg];
      else if (r16 == 8) asp[node * 8 + 4] = amc * (1.f / 32767.f);
      short* dq = &hq[(size_t)node * 128 + r16];
#pragma unroll
      for (int nt = 0; nt < 8; nt++)
        dq[nt * 16] = (short)__float2int_rn(acc[nt][reg] * rq);
    }
  }
}

// ---------------- gather-aggregate: 3-deep pipeline (round-7 best config) ----------------
__global__ __launch_bounds__(256) void k_gather(const short* __restrict__ hq,
    const float* __restrict__ asp,
    const float4* __restrict__ adst,
    const int* __restrict__ degv, const ushort* __restrict__ srcs,
    const float* __restrict__ bias, float* __restrict__ outf) {
  __shared__ alignas(16) int   s_src[2][4][4][16];
  __shared__ alignas(16) float s_wt[2][4][4][4][20];

  int wave = threadIdx.x >> 6, lane = threadIdx.x & 63;
  int grp = lane >> 4;
  int gl = lane & 15;
  int node = blockIdx.x * 16 + wave * 4 + grp;
  int head = gl >> 2;
  int c0 = gl << 3;

  int deg = 0, e0 = 0;
  float4 ad = make_float4(0.f, 0.f, 0.f, 0.f);
  bool valid = node < NN;
  if (valid) {
    deg = degv[node];
    e0 = node << 6;
    ad = adst[node];
  }
  int rounds = (deg + 15) >> 4;

  float acc[8];
#pragma unroll
  for (int i = 0; i < 8; i++) acc[i] = 0.f;
  float ws0 = 0.f, ws1 = 0.f, ws2 = 0.f, ws3 = 0.f;
  float wself = 0.f;

  auto loadSrc = [&](int r, int& sn, int& lv) {
    int j = (r << 4) + gl;
    lv = (j < deg);
    sn = lv ? (int)srcs[e0 + j] : 0;
  };
  auto loadAsp = [&](int sn, int lv, float4& a, float& sc) {
    if (lv) {
      a = *(const float4*)&asp[sn * 8];
      sc = asp[sn * 8 + 4];
    } else {
      a = make_float4(0.f, 0.f, 0.f, 0.f);
      sc = 0.f;
    }
  };
  auto finishWrite = [&](int b, int sn, int lv, float4 a, float sc) {
    float q0 = 0.f, q1 = 0.f, q2 = 0.f, q3 = 0.f;
    if (lv) {
      float v, w0, w1, w2, w3;
      v = a.x + ad.x; v = v > 0.f ? v : NEG * v; w0 = __expf(v);
      v = a.y + ad.y; v = v > 0.f ? v : NEG * v; w1 = __expf(v);
      v = a.z + ad.z; v = v > 0.f ? v : NEG * v; w2 = __expf(v);
      v = a.w + ad.w; v = v > 0.f ? v : NEG * v; w3 = __expf(v);
      ws0 += w0; ws1 += w1; ws2 += w2; ws3 += w3;
      q0 = w0 * sc; q1 = w1 * sc; q2 = w2 * sc; q3 = w3 * sc;
    }
    s_src[b][wave][grp][gl] = sn << 7;
    s_wt[b][wave][grp][0][gl] = q0;
    s_wt[b][wave][grp][1][gl] = q1;
    s_wt[b][wave][grp][2][gl] = q2;
    s_wt[b][wave][grp][3][gl] = q3;
  };

  auto consume = [&](int r, int b) {
    int cnt2 = deg - (r << 4);
    cnt2 = min(cnt2, 16);
    const int* srow = &s_src[b][wave][grp][0];
    const float* wrow = &s_wt[b][wave][grp][head][0];
#pragma unroll
    for (int c = 0; c < 2; ++c) {
      int k0 = c << 3;
      if (k0 < cnt2) {
        int4 sa = *(const int4*)&srow[k0];
        int4 sb = *(const int4*)&srow[k0 + 4];
        float4 wa = *(const float4*)&wrow[k0];
        float4 wb = *(const float4*)&wrow[k0 + 4];
        s16x8 qa = *(const s16x8*)&hq[sa.x + c0];
        s16x8 qb = *(const s16x8*)&hq[sa.y + c0];
        s16x8 qc = *(const s16x8*)&hq[sa.z + c0];
        s16x8 qd = *(const s16x8*)&hq[sa.w + c0];
        s16x8 qe = *(const s16x8*)&hq[sb.x + c0];
        s16x8 qf = *(const s16x8*)&hq[sb.y + c0];
        s16x8 qg = *(const s16x8*)&hq[sb.z + c0];
        s16x8 qh = *(const s16x8*)&hq[sb.w + c0];
#pragma unroll
        for (int i = 0; i < 8; i++) acc[i] = fmaf(wa.x, (float)qa[i], acc[i]);
#pragma unroll
        for (int i = 0; i < 8; i++) acc[i] = fmaf(wa.y, (float)qb[i], acc[i]);
#pragma unroll
        for (int i = 0; i < 8; i++) acc[i] = fmaf(wa.z, (float)qc[i], acc[i]);
#pragma unroll
        for (int i = 0; i < 8; i++) acc[i] = fmaf(wa.w, (float)qd[i], acc[i]);
        if (k0 + 4 < cnt2) {
#pragma unroll
          for (int i = 0; i < 8; i++) acc[i] = fmaf(wb.x, (float)qe[i], acc[i]);
#pragma unroll
          for (int i = 0; i < 8; i++) acc[i] = fmaf(wb.y, (float)qf[i], acc[i]);
#pragma unroll
          for (int i = 0; i < 8; i++) acc[i] = fmaf(wb.z, (float)qg[i], acc[i]);
#pragma unroll
          for (int i = 0; i < 8; i++) acc[i] = fmaf(wb.w, (float)qh[i], acc[i]);
        }
      }
    }
  };

  int sn0 = 0, lv0 = 0, sn1 = 0, lv1 = 0, sn2 = 0, lv2 = 0;
  float4 a0; float sc0;

  if (rounds > 0) {
    loadSrc(0, sn0, lv0);
    if (rounds > 1) loadSrc(1, sn1, lv1);
    loadAsp(sn0, lv0, a0, sc0);
  }

  if (valid) {
    const float4 a = *(const float4*)&asp[node * 8];
    float sc = asp[node * 8 + 4];
    float v, w0, w1, w2, w3;
    v = a.x + ad.x; v = v > 0.f ? v : NEG * v; w0 = __expf(v);
    v = a.y + ad.y; v = v > 0.f ? v : NEG * v; w1 = __expf(v);
    v = a.z + ad.z; v = v > 0.f ? v : NEG * v; w2 = __expf(v);
    v = a.w + ad.w; v = v > 0.f ? v : NEG * v; w3 = __expf(v);
    float wh = (head == 0) ? w0 : (head == 1) ? w1 : (head == 2) ? w2 : w3;
    wself = wh;
    float wssc = wh * sc;
    s16x8 qs = *(const s16x8*)&hq[(node << 7) + c0];
#pragma unroll
    for (int i = 0; i < 8; i++) acc[i] = wssc * (float)qs[i];
  }

  if (rounds > 0) {
    finishWrite(0, sn0, lv0, a0, sc0);
    for (int r = 0; r < rounds; ++r) {
      int b = r & 1;
      if (r + 2 < rounds) loadSrc(r + 2, sn2, lv2);
      float4 aX = make_float4(0.f, 0.f, 0.f, 0.f); float scX = 0.f;
      if (r + 1 < rounds) loadAsp(sn1, lv1, aX, scX);
      consume(r, b);
      if (r + 1 < rounds) finishWrite(b ^ 1, sn1, lv1, aX, scX);
      sn1 = sn2; lv1 = lv2;
    }
  }

#pragma unroll
  for (int off = 1; off < 16; off <<= 1) {
    ws0 += __shfl_xor(ws0, off);
    ws1 += __shfl_xor(ws1, off);
    ws2 += __shfl_xor(ws2, off);
    ws3 += __shfl_xor(ws3, off);
  }

  if (valid) {
    float wsum = wself + ((head == 0) ? ws0 : (head == 1) ? ws1 : (head == 2) ? ws2 : ws3);
    float rcp = 1.f / (wsum + 1e-16f);
    float4 bv0 = *(const float4*)&bias[c0];
    float4 bv1 = *(const float4*)&bias[c0 + 4];
    float bb[8] = {bv0.x, bv0.y, bv0.z, bv0.w, bv1.x, bv1.y, bv1.z, bv1.w};
    float o[8];
#pragma unroll
    for (int i = 0; i < 8; i++) {
      float v = acc[i] * rcp + bb[i];
      o[i] = v > 0.f ? v : expm1f(v);
    }
    *(float4*)&outf[(size_t)node * 128 + c0] = make_float4(o[0], o[1], o[2], o[3]);
    *(float4*)&outf[(size_t)node * 128 + c0 + 4] = make_float4(o[4], o[5], o[6], o[7]);
  }
}

// ---------------- mean pool (round-7 config: 32 nodes/block, boundary atomics) ----------------
__global__ __launch_bounds__(128) void k_pool(const float* __restrict__ feat,
    const int* __restrict__ batch, float* __restrict__ pooled, float* __restrict__ cnt) {
  int n0 = blockIdx.x * 32;
  int c = threadIdx.x;
  float acc = 0.f; int curg = -1;
  for (int i = 0; i < 32; i++) {
    int n = n0 + i;
    if (n >= NN) break;
    int g = batch[n];
    if (g != curg) {
      if (curg >= 0) atomicAdd(&pooled[curg * 128 + c], acc);
      acc = 0.f; curg = g;
    }
    acc += feat[n * 128 + c];
  }
  if (curg >= 0) atomicAdd(&pooled[curg * 128 + c], acc);
  if (threadIdx.x == 0) {
    float cc = 0.f; int cg = -1;
    for (int i = 0; i < 32; i++) {
      int n = n0 + i;
      if (n >= NN) break;
      int g = batch[n];
      if (g != cg) { if (cg >= 0) atomicAdd(&cnt[cg], cc); cc = 0.f; cg = g; }
      cc += 1.f;
    }
    if (cg >= 0) atomicAdd(&cnt[cg], cc);
  }
}

// ---------------- final FC ----------------
__global__ __launch_bounds__(128) void k_fc(const float* __restrict__ pooled,
    const float* __restrict__ cnt, const float* __restrict__ fcW,
    const float* __restrict__ fcb, float* __restrict__ out) {
  int g = blockIdx.x;
  __shared__ float p[128];
  int t = threadIdx.x;
  float inv = 1.0f / fmaxf(cnt[g], 1.0f);
  p[t] = pooled[g * 128 + t] * inv;
  __syncthreads();
  if (t < OUTC) {
    float acc = fcb[t];
    const float4* wr = (const float4*)&fcW[t * 128];
    const float4* pp = (const float4*)p;
#pragma unroll
    for (int i = 0; i < 32; i++) {
      float4 w = wr[i], pv = pp[i];
      acc = fmaf(w.x, pv.x, fmaf(w.y, pv.y, fmaf(w.z, pv.z, fmaf(w.w, pv.w, acc))));
    }
    out[g * OUTC + t] = acc;
  }
}

extern "C" void kernel_launch(void* const* d_in, const int* in_sizes, int n_in,
                              void* d_out, int out_size, void* d_ws, size_t ws_size,
                              hipStream_t stream) {
  const float* x    = (const float*)d_in[0];
  const int*   ei   = (const int*)d_in[1];
  const int*   batch= (const int*)d_in[2];
  const float* W1   = (const float*)d_in[3];
  const float* as1  = (const float*)d_in[4];
  const float* ad1  = (const float*)d_in[5];
  const float* b1   = (const float*)d_in[6];
  const float* W2   = (const float*)d_in[7];
  const float* as2  = (const float*)d_in[8];
  const float* ad2  = (const float*)d_in[9];
  const float* b2   = (const float*)d_in[10];
  const float* W3   = (const float*)d_in[11];
  const float* as3  = (const float*)d_in[12];
  const float* ad3  = (const float*)d_in[13];
  const float* b3   = (const float*)d_in[14];
  const float* fcW  = (const float*)d_in[15];
  const float* fcb  = (const float*)d_in[16];
  float* out = (float*)d_out;

  char* p = (char*)d_ws;
  auto alloc = [&](size_t bytes) { char* r = p; p += (bytes + 255) & ~(size_t)255; return r; };
  short* hq     = (short*)alloc((size_t)NN * 128 * 2);
  float* asp    = (float*)alloc((size_t)NN * 8 * 4);
  float* buf0   = (float*)alloc((size_t)NN * 128 * 4);
  float* adstv  = (float*)alloc((size_t)NN * 4 * 4);
  int*   degv   = (int*)alloc((size_t)NN * 4);
  char*  zbase  = p;
  int*   cursor = (int*)alloc((size_t)NN * CSTRIDE * 4);   // 64B line per node
  float* pooled = (float*)alloc((size_t)GG * 128 * 4);
  float* cnt    = (float*)alloc((size_t)GG * 4);
  size_t zlen   = (size_t)(p - zbase);
  ushort* srcs  = (ushort*)alloc((size_t)NN * STRIDE * 2);
  ushort* wg    = (ushort*)alloc((size_t)3 * WLAYER * 2);

  hipMemsetAsync(zbase, 0, zlen, stream);

  k_scatter_prep<<<SCAT_BLOCKS + 204, 256, 0, stream>>>(ei, cursor, srcs,
      W1, W2, W3, as1, as2, as3, ad1, ad2, ad3, wg);
  k_deg<<<(NN + 511) / 512, 512, 0, stream>>>(cursor, degv);

  const float* bs[3] = {b1, b2, b3};
  const float* fin = x;
  for (int l = 0; l < 3; l++) {
    k_gemm_mfma<<<(NN + 127) / 128, 512, 0, stream>>>(fin,
        wg + (size_t)l * WLAYER, hq, asp, adstv);
    k_gather<<<(NN + 15) / 16, 256, 0, stream>>>(hq, asp,
        (const float4*)adstv, degv, srcs, bs[l], buf0);
    fin = buf0;
  }
  k_pool<<<(NN + 31) / 32, 128, 0, stream>>>(buf0, batch, pooled, cnt);
  k_fc<<<GG, 128, 0, stream>>>(pooled, cnt, fcW, fcb, out);
}